// Round 1
// baseline (766.007 us; speedup 1.0000x reference)
//
#include <hip/hip_runtime.h>
#include <hip/hip_bf16.h>

#define TOK 4096   // tokens routed to this expert (B)
#define NTOK 8192  // dispatch buffer tokens
#define HD  2048   // hidden dim (K of gemm1, N of gemm2)
#define FF  8192   // ffn dim    (N of gemm1, K of gemm2)

typedef short bf16x8 __attribute__((ext_vector_type(8)));
typedef float f32x4  __attribute__((ext_vector_type(4)));

// fp32 -> bf16 round-to-nearest-even
__device__ __forceinline__ unsigned short f2bf(float f) {
  unsigned int u = __float_as_uint(f);
  unsigned int r = (u + 0x7FFFu + ((u >> 16) & 1u)) >> 16;
  return (unsigned short)r;
}

// async global->LDS, 16B per lane. LDS dest must be wave-uniform (HW adds lane*16).
__device__ __forceinline__ void gld16(const void* g, void* l) {
  __builtin_amdgcn_global_load_lds(
      (const __attribute__((address_space(1))) unsigned int*)g,
      (__attribute__((address_space(3))) unsigned int*)l, 16, 0, 0);
}

// ---------------- gather + fp32->bf16 cast of routed tokens ----------------
__global__ __launch_bounds__(256) void k_gather_cast(
    const float* __restrict__ hs, const int* __restrict__ idx,
    unsigned short* __restrict__ xb) {
  int t = blockIdx.x * blockDim.x + threadIdx.x;  // TOK * HD/4 threads
  int row = t >> 9;            // HD/4 = 512 chunks per row
  int c4  = (t & 511) << 2;
  long src = idx[row];
  float4 v = *reinterpret_cast<const float4*>(hs + src * HD + c4);
  ushort4 o;
  o.x = f2bf(v.x); o.y = f2bf(v.y); o.z = f2bf(v.z); o.w = f2bf(v.w);
  *reinterpret_cast<ushort4*>(xb + (size_t)row * HD + c4) = o;
}

// ---------------- fp32 [R][C] -> bf16 [C][R] tiled transpose ----------------
__global__ __launch_bounds__(256) void k_transpose_cast(
    const float* __restrict__ W, unsigned short* __restrict__ WT, int R, int C) {
  __shared__ unsigned short tile[64][65];
  int tx = threadIdx.x & 15;   // 16 col-chunks of 4
  int ty = threadIdx.x >> 4;
  int r0 = blockIdx.y * 64, c0 = blockIdx.x * 64;
#pragma unroll
  for (int i = 0; i < 4; ++i) {
    int r = ty + i * 16;
    float4 v = *reinterpret_cast<const float4*>(W + (size_t)(r0 + r) * C + c0 + tx * 4);
    tile[tx * 4 + 0][r] = f2bf(v.x);
    tile[tx * 4 + 1][r] = f2bf(v.y);
    tile[tx * 4 + 2][r] = f2bf(v.z);
    tile[tx * 4 + 3][r] = f2bf(v.w);
  }
  __syncthreads();
#pragma unroll
  for (int i = 0; i < 4; ++i) {
    int c = ty + i * 16;  // row of WT tile
    ushort4 o;
    o.x = tile[c][tx * 4 + 0]; o.y = tile[c][tx * 4 + 1];
    o.z = tile[c][tx * 4 + 2]; o.w = tile[c][tx * 4 + 3];
    *reinterpret_cast<ushort4*>(WT + (size_t)(c0 + c) * R + r0 + tx * 4) = o;
  }
}

// ---------------- GEMM1 fused: g = x@W1, u = x@W3, h = silu(g)*u (bf16) ----
// x: [TOK][HD] bf16, w1t/w3t: [FF][HD] bf16 (N-major, K-contig), h: [TOK][FF] bf16
__global__ __launch_bounds__(256) void k_gemm1(
    const unsigned short* __restrict__ xb, const unsigned short* __restrict__ w1t,
    const unsigned short* __restrict__ w3t, unsigned short* __restrict__ hb) {
  __shared__ unsigned short lds[2][3 * 4096];  // [dbuf][A|B1|B3], 48 KiB
  const int tid = threadIdx.x;
  const int w = tid >> 6, lane = tid & 63;
  const int wr = w >> 1, wc = w & 1;
  const int bx = blockIdx.x, by = blockIdx.y;  // bx: FF tile (64), by: token tile (32)

  const unsigned short* ga = xb  + (size_t)(by * 128) * HD;
  const unsigned short* g1 = w1t + (size_t)(bx * 128) * HD;
  const unsigned short* g3 = w3t + (size_t)(bx * 128) * HD;

  f32x4 accg[4][4], accu[4][4];
#pragma unroll
  for (int m = 0; m < 4; ++m)
#pragma unroll
    for (int n = 0; n < 4; ++n) {
      accg[m][n] = (f32x4){0.f, 0.f, 0.f, 0.f};
      accu[m][n] = (f32x4){0.f, 0.f, 0.f, 0.f};
    }

  auto stage = [&](int b, int k0) {
    unsigned short* L = &lds[b][0];
#pragma unroll
    for (int i = 0; i < 2; ++i) {
      int cb = i * 256 + w * 64;      // wave-uniform chunk base
      int c  = cb + lane;             // 16B chunk id: row = c>>2, kslot = c&3
      size_t go = (size_t)(c >> 2) * HD + k0 + (c & 3) * 8;
      gld16(ga + go, L + cb * 8);
      gld16(g1 + go, L + 4096 + cb * 8);
      gld16(g3 + go, L + 8192 + cb * 8);
    }
  };

  stage(0, 0);
  __syncthreads();
  int cur = 0;
  const int ro = lane & 15, ko = (lane >> 4) * 8;
  for (int t = 0; t < HD / 32; ++t) {
    if (t < HD / 32 - 1) stage(cur ^ 1, (t + 1) * 32);  // prefetch next tile
    const unsigned short* L = &lds[cur][0];
    bf16x8 af[4], b1[4], b3[4];
#pragma unroll
    for (int m = 0; m < 4; ++m)
      af[m] = *(const bf16x8*)(L + (wr * 64 + m * 16 + ro) * 32 + ko);
#pragma unroll
    for (int n = 0; n < 4; ++n) {
      b1[n] = *(const bf16x8*)(L + 4096 + (wc * 64 + n * 16 + ro) * 32 + ko);
      b3[n] = *(const bf16x8*)(L + 8192 + (wc * 64 + n * 16 + ro) * 32 + ko);
    }
#pragma unroll
    for (int m = 0; m < 4; ++m)
#pragma unroll
      for (int n = 0; n < 4; ++n) {
        accg[m][n] = __builtin_amdgcn_mfma_f32_16x16x32_bf16(af[m], b1[n], accg[m][n], 0, 0, 0);
        accu[m][n] = __builtin_amdgcn_mfma_f32_16x16x32_bf16(af[m], b3[n], accu[m][n], 0, 0, 0);
      }
    __syncthreads();
    cur ^= 1;
  }

  const int col0 = bx * 128 + wc * 64 + ro;
  const int row0 = by * 128 + wr * 64 + (lane >> 4) * 4;
#pragma unroll
  for (int m = 0; m < 4; ++m)
#pragma unroll
    for (int n = 0; n < 4; ++n)
#pragma unroll
      for (int r = 0; r < 4; ++r) {
        float g = accg[m][n][r], u = accu[m][n][r];
        float s = g / (1.f + __expf(-g));   // silu
        hb[(size_t)(row0 + m * 16 + r) * FF + col0 + n * 16] = f2bf(s * u);
      }
}

// ---------------- GEMM2: out = (h @ W2) * rw,  fp32 out ----------------
// h: [TOK][FF] bf16, w2t: [HD][FF] bf16, out: [TOK][HD] fp32
__global__ __launch_bounds__(256) void k_gemm2(
    const unsigned short* __restrict__ hb, const unsigned short* __restrict__ w2t,
    const float* __restrict__ rw, float* __restrict__ out) {
  __shared__ unsigned short lds[2][2 * 4096];  // 32 KiB
  const int tid = threadIdx.x;
  const int w = tid >> 6, lane = tid & 63;
  const int wr = w >> 1, wc = w & 1;
  const int bx = blockIdx.x, by = blockIdx.y;  // bx: HD tile (16), by: token tile (32)

  const unsigned short* ga = hb  + (size_t)(by * 128) * FF;
  const unsigned short* gb = w2t + (size_t)(bx * 128) * FF;

  f32x4 acc[4][4];
#pragma unroll
  for (int m = 0; m < 4; ++m)
#pragma unroll
    for (int n = 0; n < 4; ++n) acc[m][n] = (f32x4){0.f, 0.f, 0.f, 0.f};

  auto stage = [&](int b, int k0) {
    unsigned short* L = &lds[b][0];
#pragma unroll
    for (int i = 0; i < 2; ++i) {
      int cb = i * 256 + w * 64;
      int c  = cb + lane;
      size_t go = (size_t)(c >> 2) * FF + k0 + (c & 3) * 8;
      gld16(ga + go, L + cb * 8);
      gld16(gb + go, L + 4096 + cb * 8);
    }
  };

  stage(0, 0);
  __syncthreads();
  int cur = 0;
  const int ro = lane & 15, ko = (lane >> 4) * 8;
  for (int t = 0; t < FF / 32; ++t) {
    if (t < FF / 32 - 1) stage(cur ^ 1, (t + 1) * 32);
    const unsigned short* L = &lds[cur][0];
    bf16x8 af[4], bf[4];
#pragma unroll
    for (int m = 0; m < 4; ++m)
      af[m] = *(const bf16x8*)(L + (wr * 64 + m * 16 + ro) * 32 + ko);
#pragma unroll
    for (int n = 0; n < 4; ++n)
      bf[n] = *(const bf16x8*)(L + 4096 + (wc * 64 + n * 16 + ro) * 32 + ko);
#pragma unroll
    for (int m = 0; m < 4; ++m)
#pragma unroll
      for (int n = 0; n < 4; ++n)
        acc[m][n] = __builtin_amdgcn_mfma_f32_16x16x32_bf16(af[m], bf[n], acc[m][n], 0, 0, 0);
    __syncthreads();
    cur ^= 1;
  }

  const int col0 = bx * 128 + wc * 64 + ro;
  const int row0 = by * 128 + wr * 64 + (lane >> 4) * 4;
#pragma unroll
  for (int m = 0; m < 4; ++m)
#pragma unroll
    for (int r = 0; r < 4; ++r) {
      int row = row0 + m * 16 + r;
      float rwv = rw[row];
#pragma unroll
      for (int n = 0; n < 4; ++n)
        out[(size_t)row * HD + col0 + n * 16] = acc[m][n][r] * rwv;
    }
}

extern "C" void kernel_launch(void* const* d_in, const int* in_sizes, int n_in,
                              void* d_out, int out_size, void* d_ws, size_t ws_size,
                              hipStream_t stream) {
  const float* hs  = (const float*)d_in[0];
  const int*   idx = (const int*)d_in[1];
  const float* rw  = (const float*)d_in[2];
  const float* W1  = (const float*)d_in[3];
  const float* W3  = (const float*)d_in[4];
  const float* W2  = (const float*)d_in[5];
  float* out = (float*)d_out;

  // workspace carve (bf16 buffers): 16 + 32 + 32 + 32 + 64 = 176 MiB
  unsigned short* xb  = (unsigned short*)d_ws;
  unsigned short* w1t = xb  + (size_t)TOK * HD;
  unsigned short* w3t = w1t + (size_t)FF * HD;
  unsigned short* w2t = w3t + (size_t)FF * HD;
  unsigned short* hbf = w2t + (size_t)HD * FF;

  k_gather_cast<<<dim3((TOK * (HD / 4)) / 256), dim3(256), 0, stream>>>(hs, idx, xb);
  k_transpose_cast<<<dim3(FF / 64, HD / 64), dim3(256), 0, stream>>>(W1, w1t, HD, FF);
  k_transpose_cast<<<dim3(FF / 64, HD / 64), dim3(256), 0, stream>>>(W3, w3t, HD, FF);
  k_transpose_cast<<<dim3(HD / 64, FF / 64), dim3(256), 0, stream>>>(W2, w2t, FF, HD);
  k_gemm1<<<dim3(FF / 128, TOK / 128), dim3(256), 0, stream>>>(xb, w1t, w3t, hbf);
  k_gemm2<<<dim3(HD / 128, TOK / 128), dim3(256), 0, stream>>>(hbf, w2t, rw, out);
}